// Round 1
// 381.397 us; speedup vs baseline: 1.0124x; 1.0124x over previous
//
#include <hip/hip_runtime.h>

#define T_STEPS 20
#define B_SIZE  1024
#define D_SIZE  2312
#define BD      (B_SIZE * D_SIZE)          // 2,367,488
#define BLOCK   256
#define ROW_F4  (D_SIZE / 4)               // 578 float4 per row (exact)
#define ROWS_PER_BLOCK 4                   // one wave (64 lanes) per row

// ws layout (floats):
//   acc[t]  at ws[32*t], t<20 (padded 128B apart for atomic spread)
//   ent[t*B+b] at ws[1024 + t*1024 + b]  (20480 floats)
//   geff[d] at ws[21504 + d]             (2312 floats)
#define ACC_STRIDE 32
#define ENT_OFF    1024
#define GEFF_OFF   (ENT_OFF + T_STEPS * B_SIZE)   // 21504
#define WS_WORDS   (GEFF_OFF + D_SIZE)            // 23816 floats ~ 95 KB

typedef float floatx4 __attribute__((ext_vector_type(4)));

__device__ __forceinline__ float sigmoidf_(float x) {
    return 1.0f / (1.0f + __expf(-x));
}

// ---- wave-wide (64-lane) butterfly reductions: no LDS, no barriers ----
__device__ __forceinline__ float waveReduceMax(float v) {
    #pragma unroll
    for (int o = 32; o > 0; o >>= 1) v = fmaxf(v, __shfl_xor(v, o, 64));
    return v;
}

__device__ __forceinline__ float waveReduceSum(float v) {
    #pragma unroll
    for (int o = 32; o > 0; o >>= 1) v += __shfl_xor(v, o, 64);
    return v;
}

__device__ __forceinline__ void waveReduceSum2(float& a, float& b) {
    #pragma unroll
    for (int o = 32; o > 0; o >>= 1) {
        a += __shfl_xor(a, o, 64);
        b += __shfl_xor(b, o, 64);
    }
}

// Zero acc slots + precompute geff[d] = sigmoid(tw[d])*sigmoid(ig[d]).
__global__ void prep_kernel(const float* __restrict__ tw, const float* __restrict__ ig,
                            float* __restrict__ ws) {
    const int i = blockIdx.x * BLOCK + threadIdx.x;
    if (i < T_STEPS * ACC_STRIDE) ws[i] = 0.0f;
    if (i < D_SIZE) ws[GEFF_OFF + i] = sigmoidf_(tw[i]) * sigmoidf_(ig[i]);
}

// One WAVE per (t,b) row: softmax entropy + sum|compressed| -> acc[t], ent[t,b].
// Row x held in 10 float4 registers per lane (578 = 9*64 + 2, lanes 0-1 take
// the 2-float4 tail). All reductions are shuffle butterflies — zero LDS/barriers.
__global__ void __launch_bounds__(BLOCK)
phase1_entropy(const float* __restrict__ x, const float* __restrict__ ac,
               float* __restrict__ ws) {
    const int lane = threadIdx.x & 63;
    const int tb   = blockIdx.x * ROWS_PER_BLOCK + (threadIdx.x >> 6);  // t*B + b
    const int t    = tb >> 10;                                          // B = 1024
    const bool tail = (lane < (ROW_F4 - 9 * 64));                       // lane < 2

    const float4* __restrict__ xr = (const float4*)(x + (size_t)tb * D_SIZE);

    float4 xv[10];
    float m_l = -1e30f;
    #pragma unroll
    for (int k = 0; k < 9; ++k) {
        xv[k] = xr[lane + (k << 6)];
        m_l = fmaxf(fmaxf(m_l, fmaxf(xv[k].x, xv[k].y)),
                    fmaxf(xv[k].z, xv[k].w));
    }
    xv[9] = tail ? xr[576 + lane]
                 : make_float4(-1e30f, -1e30f, -1e30f, -1e30f);
    m_l = fmaxf(fmaxf(m_l, fmaxf(xv[9].x, xv[9].y)),
                fmaxf(xv[9].z, xv[9].w));
    const float m = waveReduceMax(m_l);

    float Z = 0.0f, W = 0.0f;
    #pragma unroll
    for (int k = 0; k < 10; ++k) {
        const float u0 = xv[k].x - m, u1 = xv[k].y - m;
        const float u2 = xv[k].z - m, u3 = xv[k].w - m;
        const float e0 = __expf(u0), e1 = __expf(u1);
        const float e2 = __expf(u2), e3 = __expf(u3);
        Z += (e0 + e1) + (e2 + e3);
        W += (e0 * u0 + e1 * u1) + (e2 * u2 + e3 * u3);  // exp(-huge)=0 kills tail
    }
    waveReduceSum2(Z, W);
    const float H = __logf(Z) - W / Z;   // ref's +1e-8 inside log: <=2e-5 error

    const float4* __restrict__ ac4 = (const float4*)ac;
    const float4* __restrict__ g4  = (const float4*)(ws + GEFF_OFF);
    float s_l = 0.0f;
    #pragma unroll
    for (int k = 0; k < 9; ++k) {
        const int f = lane + (k << 6);
        const float4 a = ac4[f];
        const float4 g = g4[f];
        s_l += fabsf(xv[k].x * sigmoidf_(a.x * H) * g.x)
             + fabsf(xv[k].y * sigmoidf_(a.y * H) * g.y)
             + fabsf(xv[k].z * sigmoidf_(a.z * H) * g.z)
             + fabsf(xv[k].w * sigmoidf_(a.w * H) * g.w);
    }
    if (tail) {
        const int f = 576 + lane;
        const float4 a = ac4[f];
        const float4 g = g4[f];
        s_l += fabsf(xv[9].x * sigmoidf_(a.x * H) * g.x)
             + fabsf(xv[9].y * sigmoidf_(a.y * H) * g.y)
             + fabsf(xv[9].z * sigmoidf_(a.z * H) * g.z)
             + fabsf(xv[9].w * sigmoidf_(a.w * H) * g.w);
    }
    s_l = waveReduceSum(s_l);
    if (lane == 0) {
        atomicAdd(&ws[ACC_STRIDE * t], s_l);
        ws[ENT_OFF + tb] = H;
    }
}

// One float4 element-group per thread; LIF recurrence over t in registers.
// out is written with NON-TEMPORAL stores so the 189 MB write stream does not
// evict the L3-resident x (loaded by phase1) before phase2 re-reads it.
__global__ void __launch_bounds__(BLOCK)
phase2_lif(const float* __restrict__ x, const float* __restrict__ ac,
           const float* __restrict__ ws,
           const float* __restrict__ mdp, const float* __restrict__ sdp,
           const float* __restrict__ thp, float* __restrict__ out) {
    const int idx = blockIdx.x * BLOCK + threadIdx.x;   // float4 index
    const int e0  = idx * 4;
    const int b   = e0 / D_SIZE;             // D_SIZE % 4 == 0 -> no row straddle
    const int d0  = e0 - b * D_SIZE;

    const float md = mdp[0];
    const float sd = sdp[0];
    const float th = thp[0];
    const float invBD = 1.0f / (float)BD;

    const float4 a = *(const float4*)(ac + d0);
    const float4 g = *(const float4*)(ws + GEFF_OFF + d0);

    float i0 = 0.f, i1 = 0.f, i2 = 0.f, i3 = 0.f;
    float v0 = 0.f, v1 = 0.f, v2 = 0.f, v3 = 0.f;

    for (int t = 0; t < T_STEPS; ++t) {
        const float4 xv = *(const float4*)(x + (size_t)t * BD + e0);
        const float H  = ws[ENT_OFF + t * B_SIZE + b];
        const float bs = ws[ACC_STRIDE * t] * invBD;

        const float c0 = xv.x * sigmoidf_(a.x * H) * g.x * bs;
        const float c1 = xv.y * sigmoidf_(a.y * H) * g.y * bs;
        const float c2 = xv.z * sigmoidf_(a.z * H) * g.z * bs;
        const float c3 = xv.w * sigmoidf_(a.w * H) * g.w * bs;

        i0 = sd * i0 + c0;  v0 = md * v0 + i0;
        i1 = sd * i1 + c1;  v1 = md * v1 + i1;
        i2 = sd * i2 + c2;  v2 = md * v2 + i2;
        i3 = sd * i3 + c3;  v3 = md * v3 + i3;

        const float s0 = sigmoidf_(v0 - th);
        const float s1 = sigmoidf_(v1 - th);
        const float s2 = sigmoidf_(v2 - th);
        const float s3 = sigmoidf_(v3 - th);
        v0 -= s0 * th;  v1 -= s1 * th;  v2 -= s2 * th;  v3 -= s3 * th;

        floatx4 sv = { s0, s1, s2, s3 };
        __builtin_nontemporal_store(sv, (floatx4*)(out + (size_t)t * BD + e0));
    }
}

extern "C" void kernel_launch(void* const* d_in, const int* in_sizes, int n_in,
                              void* d_out, int out_size, void* d_ws, size_t ws_size,
                              hipStream_t stream) {
    const float* x   = (const float*)d_in[0];
    const float* ac  = (const float*)d_in[1];
    const float* tw  = (const float*)d_in[2];
    const float* ig  = (const float*)d_in[3];
    const float* mdp = (const float*)d_in[4];
    const float* sdp = (const float*)d_in[5];
    const float* thp = (const float*)d_in[6];
    float* out = (float*)d_out;
    float* ws  = (float*)d_ws;

    // ws poisoned 0xAA each timed call — prep rewrites everything phase1/2 read.
    prep_kernel<<<10, BLOCK, 0, stream>>>(tw, ig, ws);

    phase1_entropy<<<(T_STEPS * B_SIZE) / ROWS_PER_BLOCK, BLOCK, 0, stream>>>(x, ac, ws);

    phase2_lif<<<BD / 4 / BLOCK, BLOCK, 0, stream>>>(x, ac, ws, mdp, sdp, thp, out);
}

// Round 3
// 372.668 us; speedup vs baseline: 1.0361x; 1.0234x over previous
//
#include <hip/hip_runtime.h>

#define T_STEPS 20
#define B_SIZE  1024
#define D_SIZE  2312
#define BD      (B_SIZE * D_SIZE)          // 2,367,488
#define BLOCK   256
#define ROW_F4  (D_SIZE / 4)               // 578 float4 per row (exact)
#define ROWS_PER_BLOCK 4                   // one wave (64 lanes) per row
#define PART_N  (B_SIZE / ROWS_PER_BLOCK)  // 256 phase1 blocks per timestep

// ws layout (floats) — every slot phase2 reads is plain-stored by phase1 each
// call (no atomics, no zero-init), so the 0xAA poison can never leak through:
//   part[t*256+j] at ws[blockIdx]            (5120 floats)
//   ent[t*B+b]    at ws[ENT_OFF + t*1024+b]  (20480 floats)
#define ENT_OFF (T_STEPS * PART_N)                 // 5120
#define WS_WORDS (ENT_OFF + T_STEPS * B_SIZE)      // 25600 floats = 100 KB

typedef float floatx4 __attribute__((ext_vector_type(4)));

__device__ __forceinline__ float sigmoidf_(float x) {
    return 1.0f / (1.0f + __expf(-x));
}

// ---- 64-lane butterfly reductions: result in all lanes, no LDS/barriers ----
__device__ __forceinline__ float wredMax(float v) {
    #pragma unroll
    for (int o = 32; o > 0; o >>= 1) v = fmaxf(v, __shfl_xor(v, o, 64));
    return v;
}
__device__ __forceinline__ float wredSum(float v) {
    #pragma unroll
    for (int o = 32; o > 0; o >>= 1) v += __shfl_xor(v, o, 64);
    return v;
}
__device__ __forceinline__ void wredSum2(float& a, float& b) {
    #pragma unroll
    for (int o = 32; o > 0; o >>= 1) {
        a += __shfl_xor(a, o, 64);
        b += __shfl_xor(b, o, 64);
    }
}

// One WAVE per (t,b) row; 4 rows per block. geff computed once per block into
// LDS (all waves use the same d-range). Row x held in 10 float4 regs per lane.
// Per-block |c| partial -> distinct ws slot (plain store, no atomics).
__global__ void __launch_bounds__(BLOCK)
phase1_entropy(const float* __restrict__ x, const float* __restrict__ ac,
               const float* __restrict__ tw, const float* __restrict__ ig,
               float* __restrict__ ws) {
    __shared__ float4 g4s[ROW_F4];
    __shared__ float  ss[4];

    const int tid  = threadIdx.x;
    const int lane = tid & 63;
    const int wid  = tid >> 6;

    // ---- geff = sigmoid(tw)*sigmoid(ig) into LDS, cooperatively ----
    const float4* __restrict__ tw4 = (const float4*)tw;
    const float4* __restrict__ ig4 = (const float4*)ig;
    #pragma unroll
    for (int k = 0; k < 3; ++k) {
        const int f = tid + (k << 8);
        if (k < 2 || tid < (ROW_F4 - 2 * BLOCK)) {   // 578-512=66
            const float4 t4 = tw4[f], i4 = ig4[f];
            float4 gg;
            gg.x = sigmoidf_(t4.x) * sigmoidf_(i4.x);
            gg.y = sigmoidf_(t4.y) * sigmoidf_(i4.y);
            gg.z = sigmoidf_(t4.z) * sigmoidf_(i4.z);
            gg.w = sigmoidf_(t4.w) * sigmoidf_(i4.w);
            g4s[f] = gg;
        }
    }
    __syncthreads();

    const int tb   = (blockIdx.x << 2) | wid;   // t*B + b
    const bool tail = (lane < (ROW_F4 - 9 * 64));  // lane < 2

    const float4* __restrict__ xr = (const float4*)(x + (size_t)tb * D_SIZE);

    float4 xv[10];
    float m_l = -1e30f;
    #pragma unroll
    for (int k = 0; k < 9; ++k) {
        xv[k] = xr[lane + (k << 6)];
        m_l = fmaxf(fmaxf(m_l, fmaxf(xv[k].x, xv[k].y)),
                    fmaxf(xv[k].z, xv[k].w));
    }
    xv[9] = tail ? xr[576 + lane]
                 : make_float4(-1e30f, -1e30f, -1e30f, -1e30f);
    m_l = fmaxf(fmaxf(m_l, fmaxf(xv[9].x, xv[9].y)),
                fmaxf(xv[9].z, xv[9].w));
    const float m = wredMax(m_l);

    float Z = 0.0f, W = 0.0f;
    #pragma unroll
    for (int k = 0; k < 10; ++k) {
        const float u0 = xv[k].x - m, u1 = xv[k].y - m;
        const float u2 = xv[k].z - m, u3 = xv[k].w - m;
        const float e0 = __expf(u0), e1 = __expf(u1);
        const float e2 = __expf(u2), e3 = __expf(u3);
        Z += (e0 + e1) + (e2 + e3);
        W += (e0 * u0 + e1 * u1) + (e2 * u2 + e3 * u3);  // exp(-huge)=0 kills tail
    }
    wredSum2(Z, W);
    const float H = __logf(Z) - W / Z;   // ref's +1e-8 inside log: <=2e-5 error

    const float4* __restrict__ ac4 = (const float4*)ac;
    float s_l = 0.0f;
    #pragma unroll
    for (int k = 0; k < 9; ++k) {
        const int f = lane + (k << 6);
        const float4 a = ac4[f];
        const float4 g = g4s[f];
        s_l += fabsf(xv[k].x * sigmoidf_(a.x * H) * g.x)
             + fabsf(xv[k].y * sigmoidf_(a.y * H) * g.y)
             + fabsf(xv[k].z * sigmoidf_(a.z * H) * g.z)
             + fabsf(xv[k].w * sigmoidf_(a.w * H) * g.w);
    }
    if (tail) {
        const int f = 576 + lane;
        const float4 a = ac4[f];
        const float4 g = g4s[f];
        s_l += fabsf(xv[9].x * sigmoidf_(a.x * H) * g.x)
             + fabsf(xv[9].y * sigmoidf_(a.y * H) * g.y)
             + fabsf(xv[9].z * sigmoidf_(a.z * H) * g.z)
             + fabsf(xv[9].w * sigmoidf_(a.w * H) * g.w);
    }
    s_l = wredSum(s_l);
    if (lane == 0) {
        ss[wid] = s_l;
        ws[ENT_OFF + tb] = H;
    }
    __syncthreads();
    if (tid == 0)
        ws[blockIdx.x] = (ss[0] + ss[1]) + (ss[2] + ss[3]);   // part[t][j], distinct slot
}

// One float4 per thread; LIF recurrence over t in registers. bs[0..19] reduced
// once per block into LDS (4 waves x 5 timesteps, butterfly over 256 partials).
// out written non-temporally so the write stream doesn't evict L3-resident x.
__global__ void __launch_bounds__(BLOCK)
phase2_lif(const float* __restrict__ x, const float* __restrict__ ac,
           const float* __restrict__ tw, const float* __restrict__ ig,
           const float* __restrict__ ws,
           const float* __restrict__ mdp, const float* __restrict__ sdp,
           const float* __restrict__ thp, float* __restrict__ out) {
    __shared__ float sbs[T_STEPS];

    const int tid  = threadIdx.x;
    const int lane = tid & 63;
    const int wid  = tid >> 6;
    const float invBD = 1.0f / (float)BD;

    // ---- binding strengths: wave w reduces timesteps 5w..5w+4 ----
    #pragma unroll
    for (int q = 0; q < 5; ++q) {
        const int t = wid * 5 + q;
        float a = 0.0f;
        #pragma unroll
        for (int j = 0; j < 4; ++j) a += ws[t * PART_N + lane + (j << 6)];
        a = wredSum(a);
        if (lane == 0) sbs[t] = a * invBD;
    }
    __syncthreads();

    const int idx = blockIdx.x * BLOCK + tid;   // float4 index
    const int e0  = idx * 4;
    const int b   = e0 / D_SIZE;             // D_SIZE % 4 == 0 -> no row straddle
    const int d0  = e0 - b * D_SIZE;

    const float md = mdp[0];
    const float sd = sdp[0];
    const float th = thp[0];

    const float4 a  = *(const float4*)(ac + d0);
    const float4 t4 = *(const float4*)(tw + d0);
    const float4 i4g = *(const float4*)(ig + d0);
    float4 g;
    g.x = sigmoidf_(t4.x) * sigmoidf_(i4g.x);
    g.y = sigmoidf_(t4.y) * sigmoidf_(i4g.y);
    g.z = sigmoidf_(t4.z) * sigmoidf_(i4g.z);
    g.w = sigmoidf_(t4.w) * sigmoidf_(i4g.w);

    float i0 = 0.f, i1 = 0.f, i2 = 0.f, i3 = 0.f;
    float v0 = 0.f, v1 = 0.f, v2 = 0.f, v3 = 0.f;

    for (int t = 0; t < T_STEPS; ++t) {
        const float4 xv = *(const float4*)(x + (size_t)t * BD + e0);
        const float H  = ws[ENT_OFF + t * B_SIZE + b];
        const float bs = sbs[t];

        const float c0 = xv.x * sigmoidf_(a.x * H) * g.x * bs;
        const float c1 = xv.y * sigmoidf_(a.y * H) * g.y * bs;
        const float c2 = xv.z * sigmoidf_(a.z * H) * g.z * bs;
        const float c3 = xv.w * sigmoidf_(a.w * H) * g.w * bs;

        i0 = sd * i0 + c0;  v0 = md * v0 + i0;
        i1 = sd * i1 + c1;  v1 = md * v1 + i1;
        i2 = sd * i2 + c2;  v2 = md * v2 + i2;
        i3 = sd * i3 + c3;  v3 = md * v3 + i3;

        const float s0 = sigmoidf_(v0 - th);
        const float s1 = sigmoidf_(v1 - th);
        const float s2 = sigmoidf_(v2 - th);
        const float s3 = sigmoidf_(v3 - th);
        v0 -= s0 * th;  v1 -= s1 * th;  v2 -= s2 * th;  v3 -= s3 * th;

        floatx4 sv = { s0, s1, s2, s3 };
        __builtin_nontemporal_store(sv, (floatx4*)(out + (size_t)t * BD + e0));
    }
}

extern "C" void kernel_launch(void* const* d_in, const int* in_sizes, int n_in,
                              void* d_out, int out_size, void* d_ws, size_t ws_size,
                              hipStream_t stream) {
    const float* x   = (const float*)d_in[0];
    const float* ac  = (const float*)d_in[1];
    const float* tw  = (const float*)d_in[2];
    const float* ig  = (const float*)d_in[3];
    const float* mdp = (const float*)d_in[4];
    const float* sdp = (const float*)d_in[5];
    const float* thp = (const float*)d_in[6];
    float* out = (float*)d_out;
    float* ws  = (float*)d_ws;

    phase1_entropy<<<(T_STEPS * B_SIZE) / ROWS_PER_BLOCK, BLOCK, 0, stream>>>(
        x, ac, tw, ig, ws);

    phase2_lif<<<BD / 4 / BLOCK, BLOCK, 0, stream>>>(
        x, ac, tw, ig, ws, mdp, sdp, thp, out);
}

// Round 4
// 372.332 us; speedup vs baseline: 1.0370x; 1.0009x over previous
//
#include <hip/hip_runtime.h>

#define T_STEPS 20
#define B_SIZE  1024
#define D_SIZE  2312
#define BD      (B_SIZE * D_SIZE)          // 2,367,488
#define BLOCK   256
#define ROW_F4  (D_SIZE / 4)               // 578 float4 per row (exact)
#define ROWS_PER_BLOCK 4                   // one wave (64 lanes) per row
#define PART_N  (B_SIZE / ROWS_PER_BLOCK)  // 256 phase1 blocks per timestep

// ws layout (floats) — every slot phase2 reads is plain-stored by phase1 each
// call (no atomics, no zero-init), so the 0xAA poison can never leak through:
//   part[t*256+j] at ws[blockIdx]            (5120 floats)
//   ent[t*B+b]    at ws[ENT_OFF + t*1024+b]  (20480 floats)
#define ENT_OFF (T_STEPS * PART_N)                 // 5120
#define WS_WORDS (ENT_OFF + T_STEPS * B_SIZE)      // 25600 floats = 100 KB

typedef float floatx4 __attribute__((ext_vector_type(4)));

__device__ __forceinline__ float sigmoidf_(float x) {
    return 1.0f / (1.0f + __expf(-x));
}

// ---- 64-lane butterfly reductions: result in all lanes, no LDS/barriers ----
__device__ __forceinline__ float wredMax(float v) {
    #pragma unroll
    for (int o = 32; o > 0; o >>= 1) v = fmaxf(v, __shfl_xor(v, o, 64));
    return v;
}
__device__ __forceinline__ float wredSum(float v) {
    #pragma unroll
    for (int o = 32; o > 0; o >>= 1) v += __shfl_xor(v, o, 64);
    return v;
}
__device__ __forceinline__ void wredSum2(float& a, float& b) {
    #pragma unroll
    for (int o = 32; o > 0; o >>= 1) {
        a += __shfl_xor(a, o, 64);
        b += __shfl_xor(b, o, 64);
    }
}

// One WAVE per (t,b) row; 4 rows per block. x-row loads are ISSUED FIRST so the
// geff sigmoid pass (into LDS) runs under their latency. Per-block |c| partial
// -> distinct ws slot (plain store, no atomics).
__global__ void __launch_bounds__(BLOCK)
phase1_entropy(const float* __restrict__ x, const float* __restrict__ ac,
               const float* __restrict__ tw, const float* __restrict__ ig,
               float* __restrict__ ws) {
    __shared__ float4 g4s[ROW_F4];
    __shared__ float  ss[4];

    const int tid  = threadIdx.x;
    const int lane = tid & 63;
    const int wid  = tid >> 6;

    const int tb   = (blockIdx.x << 2) | wid;      // t*B + b
    const bool tail = (lane < (ROW_F4 - 9 * 64));  // lane < 2

    // ---- issue the long-latency x loads first ----
    const float4* __restrict__ xr = (const float4*)(x + (size_t)tb * D_SIZE);
    float4 xv[10];
    #pragma unroll
    for (int k = 0; k < 9; ++k) xv[k] = xr[lane + (k << 6)];
    xv[9] = tail ? xr[576 + lane]
                 : make_float4(-1e30f, -1e30f, -1e30f, -1e30f);

    // ---- geff = sigmoid(tw)*sigmoid(ig) into LDS while x is in flight ----
    const float4* __restrict__ tw4 = (const float4*)tw;
    const float4* __restrict__ ig4 = (const float4*)ig;
    #pragma unroll
    for (int k = 0; k < 3; ++k) {
        const int f = tid + (k << 8);
        if (k < 2 || tid < (ROW_F4 - 2 * BLOCK)) {   // 578-512=66
            const float4 t4 = tw4[f], i4 = ig4[f];
            float4 gg;
            gg.x = sigmoidf_(t4.x) * sigmoidf_(i4.x);
            gg.y = sigmoidf_(t4.y) * sigmoidf_(i4.y);
            gg.z = sigmoidf_(t4.z) * sigmoidf_(i4.z);
            gg.w = sigmoidf_(t4.w) * sigmoidf_(i4.w);
            g4s[f] = gg;
        }
    }
    __syncthreads();

    float m_l = -1e30f;
    #pragma unroll
    for (int k = 0; k < 10; ++k)
        m_l = fmaxf(fmaxf(m_l, fmaxf(xv[k].x, xv[k].y)),
                    fmaxf(xv[k].z, xv[k].w));
    const float m = wredMax(m_l);

    float Z = 0.0f, W = 0.0f;
    #pragma unroll
    for (int k = 0; k < 10; ++k) {
        const float u0 = xv[k].x - m, u1 = xv[k].y - m;
        const float u2 = xv[k].z - m, u3 = xv[k].w - m;
        const float e0 = __expf(u0), e1 = __expf(u1);
        const float e2 = __expf(u2), e3 = __expf(u3);
        Z += (e0 + e1) + (e2 + e3);
        W += (e0 * u0 + e1 * u1) + (e2 * u2 + e3 * u3);  // exp(-huge)=0 kills tail
    }
    wredSum2(Z, W);
    const float H = __logf(Z) - W / Z;   // ref's +1e-8 inside log: <=2e-5 error

    const float4* __restrict__ ac4 = (const float4*)ac;
    float s_l = 0.0f;
    #pragma unroll
    for (int k = 0; k < 9; ++k) {
        const int f = lane + (k << 6);
        const float4 a = ac4[f];
        const float4 g = g4s[f];
        s_l += fabsf(xv[k].x * sigmoidf_(a.x * H) * g.x)
             + fabsf(xv[k].y * sigmoidf_(a.y * H) * g.y)
             + fabsf(xv[k].z * sigmoidf_(a.z * H) * g.z)
             + fabsf(xv[k].w * sigmoidf_(a.w * H) * g.w);
    }
    if (tail) {
        const int f = 576 + lane;
        const float4 a = ac4[f];
        const float4 g = g4s[f];
        s_l += fabsf(xv[9].x * sigmoidf_(a.x * H) * g.x)
             + fabsf(xv[9].y * sigmoidf_(a.y * H) * g.y)
             + fabsf(xv[9].z * sigmoidf_(a.z * H) * g.z)
             + fabsf(xv[9].w * sigmoidf_(a.w * H) * g.w);
    }
    s_l = wredSum(s_l);
    if (lane == 0) {
        ss[wid] = s_l;
        ws[ENT_OFF + tb] = H;
    }
    __syncthreads();
    if (tid == 0)
        ws[blockIdx.x] = (ss[0] + ss[1]) + (ss[2] + ss[3]);   // part[t][j], distinct slot
}

// One float4 per thread; LIF recurrence over t in registers. t=0 x load and all
// parameter loads are issued BEFORE the sbs reduction so they complete under the
// barrier; x[t+1] is prefetched 1-deep inside the loop. out written non-temporally
// so the write stream doesn't evict L3-resident x.
__global__ void __launch_bounds__(BLOCK)
phase2_lif(const float* __restrict__ x, const float* __restrict__ ac,
           const float* __restrict__ tw, const float* __restrict__ ig,
           const float* __restrict__ ws,
           const float* __restrict__ mdp, const float* __restrict__ sdp,
           const float* __restrict__ thp, float* __restrict__ out) {
    __shared__ float sbs[T_STEPS];

    const int tid  = threadIdx.x;
    const int lane = tid & 63;
    const int wid  = tid >> 6;
    const float invBD = 1.0f / (float)BD;

    const int idx = blockIdx.x * BLOCK + tid;   // float4 index
    const int e0  = idx * 4;
    const int b   = e0 / D_SIZE;             // D_SIZE % 4 == 0 -> no row straddle
    const int d0  = e0 - b * D_SIZE;

    // ---- issue long-latency loads first ----
    float4 xv = *(const float4*)(x + e0);                 // t = 0
    const float4 a   = *(const float4*)(ac + d0);
    const float4 t4  = *(const float4*)(tw + d0);
    const float4 i4g = *(const float4*)(ig + d0);
    const float md = mdp[0];
    const float sd = sdp[0];
    const float th = thp[0];

    // ---- binding strengths: wave w reduces timesteps 5w..5w+4 ----
    #pragma unroll
    for (int q = 0; q < 5; ++q) {
        const int t = wid * 5 + q;
        float acc = 0.0f;
        #pragma unroll
        for (int j = 0; j < 4; ++j) acc += ws[t * PART_N + lane + (j << 6)];
        acc = wredSum(acc);
        if (lane == 0) sbs[t] = acc * invBD;
    }

    float4 g;
    g.x = sigmoidf_(t4.x) * sigmoidf_(i4g.x);
    g.y = sigmoidf_(t4.y) * sigmoidf_(i4g.y);
    g.z = sigmoidf_(t4.z) * sigmoidf_(i4g.z);
    g.w = sigmoidf_(t4.w) * sigmoidf_(i4g.w);

    __syncthreads();

    float i0 = 0.f, i1 = 0.f, i2 = 0.f, i3 = 0.f;
    float v0 = 0.f, v1 = 0.f, v2 = 0.f, v3 = 0.f;

    #pragma unroll 4
    for (int t = 0; t < T_STEPS; ++t) {
        // prefetch next timestep's x 1-deep (L3 hit rides under the LIF body)
        const float4 xn = (t + 1 < T_STEPS)
                          ? *(const float4*)(x + (size_t)(t + 1) * BD + e0)
                          : xv;
        const float H  = ws[ENT_OFF + t * B_SIZE + b];
        const float bs = sbs[t];

        const float c0 = xv.x * sigmoidf_(a.x * H) * g.x * bs;
        const float c1 = xv.y * sigmoidf_(a.y * H) * g.y * bs;
        const float c2 = xv.z * sigmoidf_(a.z * H) * g.z * bs;
        const float c3 = xv.w * sigmoidf_(a.w * H) * g.w * bs;

        i0 = sd * i0 + c0;  v0 = md * v0 + i0;
        i1 = sd * i1 + c1;  v1 = md * v1 + i1;
        i2 = sd * i2 + c2;  v2 = md * v2 + i2;
        i3 = sd * i3 + c3;  v3 = md * v3 + i3;

        const float s0 = sigmoidf_(v0 - th);
        const float s1 = sigmoidf_(v1 - th);
        const float s2 = sigmoidf_(v2 - th);
        const float s3 = sigmoidf_(v3 - th);
        v0 -= s0 * th;  v1 -= s1 * th;  v2 -= s2 * th;  v3 -= s3 * th;

        floatx4 sv = { s0, s1, s2, s3 };
        __builtin_nontemporal_store(sv, (floatx4*)(out + (size_t)t * BD + e0));

        xv = xn;
    }
}

extern "C" void kernel_launch(void* const* d_in, const int* in_sizes, int n_in,
                              void* d_out, int out_size, void* d_ws, size_t ws_size,
                              hipStream_t stream) {
    const float* x   = (const float*)d_in[0];
    const float* ac  = (const float*)d_in[1];
    const float* tw  = (const float*)d_in[2];
    const float* ig  = (const float*)d_in[3];
    const float* mdp = (const float*)d_in[4];
    const float* sdp = (const float*)d_in[5];
    const float* thp = (const float*)d_in[6];
    float* out = (float*)d_out;
    float* ws  = (float*)d_ws;

    phase1_entropy<<<(T_STEPS * B_SIZE) / ROWS_PER_BLOCK, BLOCK, 0, stream>>>(
        x, ac, tw, ig, ws);

    phase2_lif<<<BD / 4 / BLOCK, BLOCK, 0, stream>>>(
        x, ac, tw, ig, ws, mdp, sdp, thp, out);
}